// Round 2
// baseline (61.155 us; speedup 1.0000x reference)
//
#include <hip/hip_runtime.h>

#define B_ 64
#define M_ 4096
#define D_ 128
#define O_ 16

// Pass 1: u_t[b][k][o] = sum_d x1[b,d]*W[o,d,k] + v2[o,k]   (transposed layout)
//         c[b,o] = x1[b].v1[o] + bias[o]
__global__ __launch_bounds__(128) void prep_kernel(
    const float* __restrict__ x1, const float* __restrict__ W,
    const float* __restrict__ V, const float* __restrict__ bias,
    float* __restrict__ u_t, float* __restrict__ c)
{
    const int o = blockIdx.x;   // [0,16)
    const int b = blockIdx.y;   // [0,64)
    const int k = threadIdx.x;  // [0,128)
    __shared__ float x1s[D_];
    __shared__ float red[2];
    x1s[k] = x1[b * D_ + k];
    __syncthreads();

    const float* Wo = W + o * D_ * D_;
    float acc = 0.f;
    #pragma unroll 8
    for (int d = 0; d < D_; ++d)
        acc = fmaf(x1s[d], Wo[d * D_ + k], acc);   // coalesced over k

    u_t[(b * D_ + k) * O_ + o] = acc + V[o * 2 * D_ + D_ + k];  // + v2[o,k]

    float p = x1s[k] * V[o * 2 * D_ + k];
    #pragma unroll
    for (int off = 32; off; off >>= 1) p += __shfl_down(p, off, 64);
    if ((k & 63) == 0) red[k >> 6] = p;
    __syncthreads();
    if (k == 0) c[b * O_ + o] = red[0] + red[1] + bias[o];
}

// Pass 2: out[b,m,o] = relu( sum_k x2[b,m,k]*u_t[b,k,o] + c[b,o] )
// 128 threads/block, R=2 rows/thread -> 256 rows/block, grid (16, 64).
__global__ __launch_bounds__(128) void fused_kernel(
    const float* __restrict__ x2, const float* __restrict__ u_t,
    const float* __restrict__ c, float* __restrict__ out)
{
    const int b = blockIdx.y;
    const int t = threadIdx.x;                 // 0..127
    const int m0 = blockIdx.x * 256 + t;       // row A; row B = m0 + 128

    __shared__ float4 us[D_ * 4];   // u_t[b]: per k, 4 float4 (16 o) = 8 KB
    __shared__ float cs[O_];
    {
        const float4* ug = (const float4*)(u_t + (size_t)b * D_ * O_);
        #pragma unroll
        for (int i = 0; i < 4; ++i)            // 512 float4 / 128 thr
            us[t + i * 128] = ug[t + i * 128];
        if (t < O_) cs[t] = c[b * O_ + t];
    }
    __syncthreads();

    const float4* xa = (const float4*)(x2 + ((size_t)b * M_ + m0) * D_);
    const float4* xb = xa + 128 * (D_ / 4);    // row m0+128

    float acc0[O_], acc1[O_];
    #pragma unroll
    for (int o = 0; o < O_; ++o) { acc0[o] = cs[o]; acc1[o] = cs[o]; }

    #pragma unroll 4
    for (int kk = 0; kk < D_ / 4; ++kk) {
        float4 av = xa[kk];
        float4 bv = xb[kk];
        const float* af = (const float*)&av;
        const float* bf = (const float*)&bv;
        #pragma unroll
        for (int j = 0; j < 4; ++j) {
            const int k = kk * 4 + j;
            const float4* up = &us[k * 4];     // wave-uniform -> LDS broadcast
            const float xs0 = af[j];
            const float xs1 = bf[j];
            #pragma unroll
            for (int q = 0; q < 4; ++q) {
                float4 uv = up[q];             // one read feeds 8 FMAs
                acc0[q*4+0] = fmaf(xs0, uv.x, acc0[q*4+0]);
                acc0[q*4+1] = fmaf(xs0, uv.y, acc0[q*4+1]);
                acc0[q*4+2] = fmaf(xs0, uv.z, acc0[q*4+2]);
                acc0[q*4+3] = fmaf(xs0, uv.w, acc0[q*4+3]);
                acc1[q*4+0] = fmaf(xs1, uv.x, acc1[q*4+0]);
                acc1[q*4+1] = fmaf(xs1, uv.y, acc1[q*4+1]);
                acc1[q*4+2] = fmaf(xs1, uv.z, acc1[q*4+2]);
                acc1[q*4+3] = fmaf(xs1, uv.w, acc1[q*4+3]);
            }
        }
    }

    float4* op0 = (float4*)(out + ((size_t)b * M_ + m0) * O_);
    float4* op1 = op0 + 128 * (O_ / 4);
    #pragma unroll
    for (int q = 0; q < 4; ++q) {
        float4 r0, r1;
        r0.x = fmaxf(acc0[q*4+0], 0.f);
        r0.y = fmaxf(acc0[q*4+1], 0.f);
        r0.z = fmaxf(acc0[q*4+2], 0.f);
        r0.w = fmaxf(acc0[q*4+3], 0.f);
        r1.x = fmaxf(acc1[q*4+0], 0.f);
        r1.y = fmaxf(acc1[q*4+1], 0.f);
        r1.z = fmaxf(acc1[q*4+2], 0.f);
        r1.w = fmaxf(acc1[q*4+3], 0.f);
        op0[q] = r0;
        op1[q] = r1;
    }
}

extern "C" void kernel_launch(void* const* d_in, const int* in_sizes, int n_in,
                              void* d_out, int out_size, void* d_ws, size_t ws_size,
                              hipStream_t stream) {
    const float* x1   = (const float*)d_in[0];
    const float* x2   = (const float*)d_in[1];
    const float* W    = (const float*)d_in[2];
    const float* V    = (const float*)d_in[3];
    const float* bias = (const float*)d_in[4];
    float* out = (float*)d_out;

    float* u_t = (float*)d_ws;               // B*D*O floats = 512 KB
    float* c   = u_t + B_ * D_ * O_;         // B*O floats

    prep_kernel<<<dim3(O_, B_), 128, 0, stream>>>(x1, W, V, bias, u_t, c);
    fused_kernel<<<dim3(M_ / 256, B_), 128, 0, stream>>>(x2, u_t, c, out);
}

// Round 3
// 48.524 us; speedup vs baseline: 1.2603x; 1.2603x over previous
//
#include <hip/hip_runtime.h>

#define B_ 64
#define M_ 4096
#define D_ 128
#define O_ 16

// Pass 1: u_t[b][k][o] = sum_d x1[b,d]*W[o,d,k] + v2[o,k]   (k-major layout)
//         c[b,o] = x1[b].v1[o] + bias[o]
__global__ __launch_bounds__(128) void prep_kernel(
    const float* __restrict__ x1, const float* __restrict__ W,
    const float* __restrict__ V, const float* __restrict__ bias,
    float* __restrict__ u_t, float* __restrict__ c)
{
    const int o = blockIdx.x;   // [0,16)
    const int b = blockIdx.y;   // [0,64)
    const int k = threadIdx.x;  // [0,128)
    __shared__ float x1s[D_];
    __shared__ float red[2];
    x1s[k] = x1[b * D_ + k];
    __syncthreads();

    const float* Wo = W + o * D_ * D_;
    float acc = 0.f;
    #pragma unroll 8
    for (int d = 0; d < D_; ++d)
        acc = fmaf(x1s[d], Wo[d * D_ + k], acc);   // coalesced over k

    u_t[(b * D_ + k) * O_ + o] = acc + V[o * 2 * D_ + D_ + k];  // + v2[o,k]

    float p = x1s[k] * V[o * 2 * D_ + k];
    #pragma unroll
    for (int off = 32; off; off >>= 1) p += __shfl_down(p, off, 64);
    if ((k & 63) == 0) red[k >> 6] = p;
    __syncthreads();
    if (k == 0) c[b * O_ + o] = red[0] + red[1] + bias[o];
}

// Pass 2: out[b,m,o] = relu( sum_k x2[b,m,k]*u_t[b,k,o] + c[b,o] )
// 4 lanes per row (k-split, interleaved float4), 256 thr = 64 rows/block.
// Grid (64, 64) -> 16384 waves (device slots: 8192) -> occupancy not grid-limited.
__global__ __launch_bounds__(256, 7) void fused_kernel(
    const float* __restrict__ x2, const float* __restrict__ u_t,
    const float* __restrict__ c, float* __restrict__ out)
{
    const int b = blockIdx.y;
    const int t = threadIdx.x;        // 0..255
    const int r = t >> 2;             // row within block, 0..63
    const int j = t & 3;              // k-quarter lane, 0..3
    const int m = blockIdx.x * 64 + r;

    // u[b] staged twice (copy per j parity) -> 4 distinct ds addrs fall as
    // 2-way bank alias (free, m136). 2*2056 floats = 16.4 KB.
    __shared__ float us[2 * 2056];
    {
        const float4* ug = (const float4*)(u_t + (size_t)b * (D_ * O_));
        float4* s0 = (float4*)us;
        float4* s1 = (float4*)(us + 2056);
        #pragma unroll
        for (int i = 0; i < 2; ++i) {
            float4 v = ug[t + i * 256];
            s0[t + i * 256] = v;
            s1[t + i * 256] = v;
        }
    }
    __syncthreads();

    // Coalesced x2: lane (r,j) reads float4 idx it*4+j -> per instr the wave
    // covers 16 rows x 64B contiguous = 16 full lines. All 8 issued up front.
    const float4* xr = (const float4*)x2 + ((size_t)b * M_ + m) * (D_ / 4);
    float4 xv[8];
    #pragma unroll
    for (int it = 0; it < 8; ++it)
        xv[it] = xr[it * 4 + j];

    float acc[O_];
    #pragma unroll
    for (int o = 0; o < O_; ++o) acc[o] = 0.f;

    const float* ub = us + (j & 1) * 2056;
    #pragma unroll
    for (int it = 0; it < 8; ++it) {
        const int k0 = it * 16 + j * 4;          // this float4's first k
        const float* xf = (const float*)&xv[it];
        #pragma unroll
        for (int e = 0; e < 4; ++e) {
            const float4* up = (const float4*)(ub + (size_t)(k0 + e) * O_);
            const float xs = xf[e];
            #pragma unroll
            for (int q = 0; q < 4; ++q) {
                float4 uv = up[q];
                acc[q*4+0] = fmaf(xs, uv.x, acc[q*4+0]);
                acc[q*4+1] = fmaf(xs, uv.y, acc[q*4+1]);
                acc[q*4+2] = fmaf(xs, uv.z, acc[q*4+2]);
                acc[q*4+3] = fmaf(xs, uv.w, acc[q*4+3]);
            }
        }
    }

    // Butterfly over the 4 k-lanes: all 4 end with full row sums.
    #pragma unroll
    for (int o = 0; o < O_; ++o) acc[o] += __shfl_xor(acc[o], 1, 64);
    #pragma unroll
    for (int o = 0; o < O_; ++o) acc[o] += __shfl_xor(acc[o], 2, 64);

    // Lane j stores o-quad j: static-index select (no runtime array index).
    float4 c4 = ((const float4*)(c + b * O_))[j];
    float4 rv;
    rv.x = (j == 0) ? acc[0] : (j == 1) ? acc[4] : (j == 2) ? acc[8]  : acc[12];
    rv.y = (j == 0) ? acc[1] : (j == 1) ? acc[5] : (j == 2) ? acc[9]  : acc[13];
    rv.z = (j == 0) ? acc[2] : (j == 1) ? acc[6] : (j == 2) ? acc[10] : acc[14];
    rv.w = (j == 0) ? acc[3] : (j == 1) ? acc[7] : (j == 2) ? acc[11] : acc[15];
    rv.x = fmaxf(rv.x + c4.x, 0.f);
    rv.y = fmaxf(rv.y + c4.y, 0.f);
    rv.z = fmaxf(rv.z + c4.z, 0.f);
    rv.w = fmaxf(rv.w + c4.w, 0.f);

    // Wave store: 16 rows x 64B = 1KB contiguous, fully coalesced.
    float4* op = (float4*)out + ((size_t)b * M_ + m) * (O_ / 4);
    op[j] = rv;
}

extern "C" void kernel_launch(void* const* d_in, const int* in_sizes, int n_in,
                              void* d_out, int out_size, void* d_ws, size_t ws_size,
                              hipStream_t stream) {
    const float* x1   = (const float*)d_in[0];
    const float* x2   = (const float*)d_in[1];
    const float* W    = (const float*)d_in[2];
    const float* V    = (const float*)d_in[3];
    const float* bias = (const float*)d_in[4];
    float* out = (float*)d_out;

    float* u_t = (float*)d_ws;               // B*D*O floats = 512 KB
    float* c   = u_t + B_ * D_ * O_;         // B*O floats

    prep_kernel<<<dim3(O_, B_), 128, 0, stream>>>(x1, W, V, bias, u_t, c);
    fused_kernel<<<dim3(M_ / 64, B_), 256, 0, stream>>>(x2, u_t, c, out);
}

// Round 4
// 40.187 us; speedup vs baseline: 1.5218x; 1.2075x over previous
//
#include <hip/hip_runtime.h>

#define B_ 64
#define M_ 4096
#define D_ 128
#define O_ 16

// Pass 1: u_t[b][k][o] = sum_d x1[b,d]*W[o,d,k] + v2[o,k]   (k-major layout)
//         c[b,o] = x1[b].v1[o] + bias[o]
__global__ __launch_bounds__(128) void prep_kernel(
    const float* __restrict__ x1, const float* __restrict__ W,
    const float* __restrict__ V, const float* __restrict__ bias,
    float* __restrict__ u_t, float* __restrict__ c)
{
    const int o = blockIdx.x;   // [0,16)
    const int b = blockIdx.y;   // [0,64)
    const int k = threadIdx.x;  // [0,128)
    __shared__ float x1s[D_];
    __shared__ float red[2];
    x1s[k] = x1[b * D_ + k];
    __syncthreads();

    const float* Wo = W + o * D_ * D_;
    float acc = 0.f;
    #pragma unroll 8
    for (int d = 0; d < D_; ++d)
        acc = fmaf(x1s[d], Wo[d * D_ + k], acc);   // coalesced over k

    u_t[(b * D_ + k) * O_ + o] = acc + V[o * 2 * D_ + D_ + k];  // + v2[o,k]

    float p = x1s[k] * V[o * 2 * D_ + k];
    #pragma unroll
    for (int off = 32; off; off >>= 1) p += __shfl_down(p, off, 64);
    if ((k & 63) == 0) red[k >> 6] = p;
    __syncthreads();
    if (k == 0) c[b * O_ + o] = red[0] + red[1] + bias[o];
}

// Pass 2: out[b,m,o] = relu( sum_k x2[b,m,k]*u_t[b,k,o] + c[b,o] )
// R=4 rows/thread, S=4 lanes/row (k-split). 256 thr -> 256 rows/block.
// Per-wave LDS reads (128 x b128) now feed 64 rows: LDS pipe ~10us total.
__global__ __launch_bounds__(256) void fused_kernel(
    const float* __restrict__ x2, const float* __restrict__ u_t,
    const float* __restrict__ c, float* __restrict__ out)
{
    const int b = blockIdx.y;
    const int t = threadIdx.x;        // 0..255
    const int j = t & 3;              // k-quarter lane
    const int rw = t >> 2;            // 0..63; thread's rows: m0 + 64*r
    const size_t m0 = (size_t)blockIdx.x * 256 + rw;

    // u[b] staged twice; j-parity copy split -> 2-way bank alias (free, m136)
    __shared__ float4 us4[2 * 514];   // 2 copies of 512 float4 (+2 pad)
    {
        const float4* ug = (const float4*)(u_t + (size_t)b * (D_ * O_));
        #pragma unroll
        for (int i = 0; i < 2; ++i) {
            float4 v = ug[t + i * 256];
            us4[t + i * 256] = v;
            us4[514 + t + i * 256] = v;
        }
    }
    __syncthreads();

    const float4* xr = (const float4*)x2 + ((size_t)b * M_ + m0) * (D_ / 4);

    float acc[4][O_];
    #pragma unroll
    for (int r = 0; r < 4; ++r)
        #pragma unroll
        for (int o = 0; o < O_; ++o) acc[r][o] = 0.f;

    const float* ub = (const float*)us4 + (j & 1) * (514 * 4);

    #pragma unroll
    for (int it = 0; it < 8; ++it) {
        // 4 rows x 16B, coalesced per wave: 16 consecutive rows x 64B chunks
        float4 xv0 = xr[0 * 64 * (D_ / 4) + it * 4 + j];
        float4 xv1 = xr[1 * 64 * (D_ / 4) + it * 4 + j];
        float4 xv2 = xr[2 * 64 * (D_ / 4) + it * 4 + j];
        float4 xv3 = xr[3 * 64 * (D_ / 4) + it * 4 + j];
        const float* xf0 = (const float*)&xv0;
        const float* xf1 = (const float*)&xv1;
        const float* xf2 = (const float*)&xv2;
        const float* xf3 = (const float*)&xv3;
        #pragma unroll
        for (int e = 0; e < 4; ++e) {
            const int k = it * 16 + j * 4 + e;
            const float4* up = (const float4*)(ub + (size_t)k * O_);
            const float a0 = xf0[e], a1 = xf1[e], a2 = xf2[e], a3 = xf3[e];
            #pragma unroll
            for (int q = 0; q < 4; ++q) {
                float4 uv = up[q];             // one b128 feeds 64 FMAs
                acc[0][q*4+0] = fmaf(a0, uv.x, acc[0][q*4+0]);
                acc[0][q*4+1] = fmaf(a0, uv.y, acc[0][q*4+1]);
                acc[0][q*4+2] = fmaf(a0, uv.z, acc[0][q*4+2]);
                acc[0][q*4+3] = fmaf(a0, uv.w, acc[0][q*4+3]);
                acc[1][q*4+0] = fmaf(a1, uv.x, acc[1][q*4+0]);
                acc[1][q*4+1] = fmaf(a1, uv.y, acc[1][q*4+1]);
                acc[1][q*4+2] = fmaf(a1, uv.z, acc[1][q*4+2]);
                acc[1][q*4+3] = fmaf(a1, uv.w, acc[1][q*4+3]);
                acc[2][q*4+0] = fmaf(a2, uv.x, acc[2][q*4+0]);
                acc[2][q*4+1] = fmaf(a2, uv.y, acc[2][q*4+1]);
                acc[2][q*4+2] = fmaf(a2, uv.z, acc[2][q*4+2]);
                acc[2][q*4+3] = fmaf(a2, uv.w, acc[2][q*4+3]);
                acc[3][q*4+0] = fmaf(a3, uv.x, acc[3][q*4+0]);
                acc[3][q*4+1] = fmaf(a3, uv.y, acc[3][q*4+1]);
                acc[3][q*4+2] = fmaf(a3, uv.z, acc[3][q*4+2]);
                acc[3][q*4+3] = fmaf(a3, uv.w, acc[3][q*4+3]);
            }
        }
    }

    // Butterfly over the 4 k-lanes: all lanes end with full row sums.
    #pragma unroll
    for (int r = 0; r < 4; ++r)
        #pragma unroll
        for (int o = 0; o < O_; ++o) {
            acc[r][o] += __shfl_xor(acc[r][o], 1, 64);
            acc[r][o] += __shfl_xor(acc[r][o], 2, 64);
        }

    const float4 c4 = ((const float4*)(c + b * O_))[j];
    float4* op = (float4*)out + ((size_t)b * M_ + m0) * (O_ / 4);
    #pragma unroll
    for (int r = 0; r < 4; ++r) {
        float4 rv;
        rv.x = (j == 0) ? acc[r][0] : (j == 1) ? acc[r][4] : (j == 2) ? acc[r][8]  : acc[r][12];
        rv.y = (j == 0) ? acc[r][1] : (j == 1) ? acc[r][5] : (j == 2) ? acc[r][9]  : acc[r][13];
        rv.z = (j == 0) ? acc[r][2] : (j == 1) ? acc[r][6] : (j == 2) ? acc[r][10] : acc[r][14];
        rv.w = (j == 0) ? acc[r][3] : (j == 1) ? acc[r][7] : (j == 2) ? acc[r][11] : acc[r][15];
        rv.x = fmaxf(rv.x + c4.x, 0.f);
        rv.y = fmaxf(rv.y + c4.y, 0.f);
        rv.z = fmaxf(rv.z + c4.z, 0.f);
        rv.w = fmaxf(rv.w + c4.w, 0.f);
        // fixed r: 16 consecutive rows x 64B -> contiguous 1KB per wave
        op[r * 64 * (O_ / 4) + j] = rv;
    }
}

extern "C" void kernel_launch(void* const* d_in, const int* in_sizes, int n_in,
                              void* d_out, int out_size, void* d_ws, size_t ws_size,
                              hipStream_t stream) {
    const float* x1   = (const float*)d_in[0];
    const float* x2   = (const float*)d_in[1];
    const float* W    = (const float*)d_in[2];
    const float* V    = (const float*)d_in[3];
    const float* bias = (const float*)d_in[4];
    float* out = (float*)d_out;

    float* u_t = (float*)d_ws;               // B*D*O floats = 512 KB
    float* c   = u_t + B_ * D_ * O_;         // B*O floats

    prep_kernel<<<dim3(O_, B_), 128, 0, stream>>>(x1, W, V, bias, u_t, c);
    fused_kernel<<<dim3(M_ / 256, B_), 256, 0, stream>>>(x2, u_t, c, out);
}

// Round 5
// 36.441 us; speedup vs baseline: 1.6782x; 1.1028x over previous
//
#include <hip/hip_runtime.h>

#define B_ 64
#define M_ 4096
#define D_ 128
#define O_ 16

typedef __bf16 bf16x8 __attribute__((ext_vector_type(8)));
typedef float  f32x4  __attribute__((ext_vector_type(4)));

// Pass 1: u[b,k,o] = sum_d x1[b,d]*W[o,d,k] + v2[o,k], emitted as bf16 in
// MFMA B-fragment order: ub[b][kb][lane][e], lane = kgroup*16 + o, k = kb*32
// + kgroup*8 + e (contiguous-8 mapping, ref-checked in m92/m97).
//         c[b,o] = x1[b].v1[o] + bias[o]
__global__ __launch_bounds__(128) void prep_kernel(
    const float* __restrict__ x1, const float* __restrict__ W,
    const float* __restrict__ V, const float* __restrict__ bias,
    __bf16* __restrict__ ub, float* __restrict__ c)
{
    const int o = blockIdx.x;   // [0,16)
    const int b = blockIdx.y;   // [0,64)
    const int k = threadIdx.x;  // [0,128)
    __shared__ float x1s[D_];
    __shared__ float red[2];
    x1s[k] = x1[b * D_ + k];
    __syncthreads();

    const float* Wo = W + o * D_ * D_;
    float acc = 0.f;
    #pragma unroll 8
    for (int d = 0; d < D_; ++d)
        acc = fmaf(x1s[d], Wo[d * D_ + k], acc);   // coalesced over k

    const float uval = acc + V[o * 2 * D_ + D_ + k];   // + v2[o,k]
    // frag-layout write: offset = b*2048 + kb*512 + kgroup*128 + o*8 + e
    const int e  = k & 7;
    const int g  = (k >> 3) & 3;
    const int kb = k >> 5;
    ub[(size_t)b * 2048 + kb * 512 + g * 128 + o * 8 + e] = (__bf16)uval;

    float p = x1s[k] * V[o * 2 * D_ + k];
    #pragma unroll
    for (int off = 32; off; off >>= 1) p += __shfl_down(p, off, 64);
    if ((k & 63) == 0) red[k >> 6] = p;
    __syncthreads();
    if (k == 0) c[b * O_ + o] = red[0] + red[1] + bias[o];
}

// Pass 2: out[b,m,o] = relu( x2[b,m,:] x u[b,:,:] + c[b,o] ) via MFMA.
// 4 waves/block, each wave does 4 tiles of 16 rows. u held in 16 VGPRs.
// k-loop: zero LDS reads, zero shuffles; 8 coalesced dwordx4 loads/tile.
__global__ __launch_bounds__(256) void fused_kernel(
    const float* __restrict__ x2, const __bf16* __restrict__ ub,
    const float* __restrict__ c, float* __restrict__ out)
{
    const int b = blockIdx.y;
    const int t = threadIdx.x;

    __shared__ bf16x8 ubs[256];   // 4 KB: this b's u fragments
    ((float4*)ubs)[t] = ((const float4*)(ub + (size_t)b * 2048))[t];
    __syncthreads();

    const int wave = t >> 6, lane = t & 63;
    const int rc = lane & 15;          // A-row / C-col (o)
    const int g  = lane >> 4;          // k-group

    bf16x8 bfrag[4];
    #pragma unroll
    for (int kb = 0; kb < 4; ++kb) bfrag[kb] = ubs[kb * 64 + lane];

    const float cv = c[b * O_ + rc];
    const int m_base = blockIdx.x * 256 + wave * 64;

    for (int tile = 0; tile < 4; ++tile) {
        const int m0 = m_base + tile * 16;
        // lane reads f32 x2[b][m0+rc][kb*32 + g*8 .. +7] = 2 float4 per kb;
        // per instr the wave covers 16 rows x full 128B lines.
        const float4* ap = (const float4*)(x2 + ((size_t)b * M_ + m0 + rc) * D_) + g * 2;

        f32x4 acc = {cv, cv, cv, cv};
        #pragma unroll
        for (int kb = 0; kb < 4; ++kb) {
            float4 a0 = ap[kb * 8];
            float4 a1 = ap[kb * 8 + 1];
            bf16x8 af;
            af[0] = (__bf16)a0.x; af[1] = (__bf16)a0.y;
            af[2] = (__bf16)a0.z; af[3] = (__bf16)a0.w;
            af[4] = (__bf16)a1.x; af[5] = (__bf16)a1.y;
            af[6] = (__bf16)a1.z; af[7] = (__bf16)a1.w;
            acc = __builtin_amdgcn_mfma_f32_16x16x32_bf16(af, bfrag[kb], acc, 0, 0, 0);
        }

        // C/D: col = lane&15 (=o), row = g*4 + i  (verified m89/m91)
        float* op = out + ((size_t)b * M_ + m0) * O_ + rc;
        #pragma unroll
        for (int i = 0; i < 4; ++i)
            op[(g * 4 + i) * O_] = fmaxf(acc[i], 0.f);
    }
}

extern "C" void kernel_launch(void* const* d_in, const int* in_sizes, int n_in,
                              void* d_out, int out_size, void* d_ws, size_t ws_size,
                              hipStream_t stream) {
    const float* x1   = (const float*)d_in[0];
    const float* x2   = (const float*)d_in[1];
    const float* W    = (const float*)d_in[2];
    const float* V    = (const float*)d_in[3];
    const float* bias = (const float*)d_in[4];
    float* out = (float*)d_out;

    __bf16* ubf = (__bf16*)d_ws;                           // 64*2048 bf16 = 256 KB
    float*  c   = (float*)((char*)d_ws + (size_t)B_ * 2048 * sizeof(__bf16));

    prep_kernel<<<dim3(O_, B_), 128, 0, stream>>>(x1, W, V, bias, ubf, c);
    fused_kernel<<<dim3(M_ / 256, B_), 256, 0, stream>>>(x2, ubf, c, out);
}

// Round 6
// 34.821 us; speedup vs baseline: 1.7562x; 1.0465x over previous
//
#include <hip/hip_runtime.h>

#define B_ 64
#define M_ 4096
#define D_ 128
#define O_ 16

typedef __bf16 bf16x8 __attribute__((ext_vector_type(8)));
typedef float  f32x4  __attribute__((ext_vector_type(4)));

// Pass 1: u[b,k,o] = sum_d x1[b,d]*W[o,d,k] + v2[o,k], emitted as bf16 in
// MFMA B-fragment order: lane = kgroup*16 + o, k = kb*32 + kgroup*8 + e.
//         c[b,o] = x1[b].v1[o] + bias[o]
__global__ __launch_bounds__(128) void prep_kernel(
    const float* __restrict__ x1, const float* __restrict__ W,
    const float* __restrict__ V, const float* __restrict__ bias,
    __bf16* __restrict__ ub, float* __restrict__ c)
{
    const int o = blockIdx.x;   // [0,16)
    const int b = blockIdx.y;   // [0,64)
    const int k = threadIdx.x;  // [0,128)
    __shared__ float x1s[D_];
    __shared__ float red[2];
    x1s[k] = x1[b * D_ + k];
    __syncthreads();

    const float* Wo = W + o * D_ * D_;
    float acc = 0.f;
    #pragma unroll 8
    for (int d = 0; d < D_; ++d)
        acc = fmaf(x1s[d], Wo[d * D_ + k], acc);   // coalesced over k

    const float uval = acc + V[o * 2 * D_ + D_ + k];   // + v2[o,k]
    const int e  = k & 7;
    const int g  = (k >> 3) & 3;
    const int kb = k >> 5;
    ub[(size_t)b * 2048 + kb * 512 + g * 128 + o * 8 + e] = (__bf16)uval;

    float p = x1s[k] * V[o * 2 * D_ + k];
    #pragma unroll
    for (int off = 32; off; off >>= 1) p += __shfl_down(p, off, 64);
    if ((k & 63) == 0) red[k >> 6] = p;
    __syncthreads();
    if (k == 0) c[b * O_ + o] = red[0] + red[1] + bias[o];
}

// Pass 2: out[b,m,o] = relu( x2[b,m,:] x u[b,:,:] + c[b,o] ) via MFMA.
// No LDS, no barriers. 2 tiles of 16 rows per wave; grid 2048 blocks
// (8192 waves = 100% of device slots). All 16 x2 loads issued up front.
__global__ __launch_bounds__(256) void fused_kernel(
    const float* __restrict__ x2, const __bf16* __restrict__ ub,
    const float* __restrict__ c, float* __restrict__ out)
{
    const int b = blockIdx.y;
    const int t = threadIdx.x;
    const int wave = t >> 6, lane = t & 63;
    const int rc = lane & 15;          // A-row / C-col (o)
    const int g  = lane >> 4;          // k-group

    // B-fragments straight from global: 1KB/wave-instr coalesced, L2-hot.
    const bf16x8* uf = (const bf16x8*)(ub + (size_t)b * 2048);
    bf16x8 bfrag[4];
    #pragma unroll
    for (int kb = 0; kb < 4; ++kb) bfrag[kb] = uf[kb * 64 + lane];
    const float cv = c[b * O_ + rc];

    const int m_base = blockIdx.x * 128 + wave * 32;
    const float4* ap0 = (const float4*)(x2 + ((size_t)b * M_ + m_base + rc) * D_) + g * 2;
    const float4* ap1 = ap0 + 16 * (D_ / 4);   // +16 rows

    float4 a0[8], a1[8];
    #pragma unroll
    for (int kb = 0; kb < 4; ++kb) {
        a0[kb * 2]     = ap0[kb * 8];
        a0[kb * 2 + 1] = ap0[kb * 8 + 1];
    }
    #pragma unroll
    for (int kb = 0; kb < 4; ++kb) {
        a1[kb * 2]     = ap1[kb * 8];
        a1[kb * 2 + 1] = ap1[kb * 8 + 1];
    }

    #pragma unroll
    for (int tt = 0; tt < 2; ++tt) {
        const float4* av = tt ? a1 : a0;
        f32x4 acc = {cv, cv, cv, cv};
        #pragma unroll
        for (int kb = 0; kb < 4; ++kb) {
            const float* p0 = (const float*)&av[kb * 2];
            bf16x8 af;
            af[0] = (__bf16)p0[0]; af[1] = (__bf16)p0[1];
            af[2] = (__bf16)p0[2]; af[3] = (__bf16)p0[3];
            af[4] = (__bf16)p0[4]; af[5] = (__bf16)p0[5];
            af[6] = (__bf16)p0[6]; af[7] = (__bf16)p0[7];
            acc = __builtin_amdgcn_mfma_f32_16x16x32_bf16(af, bfrag[kb], acc, 0, 0, 0);
        }
        // C/D: col = lane&15 (=o), row = g*4 + i  (verified m89/m91)
        float* op = out + ((size_t)b * M_ + m_base + tt * 16) * O_ + rc;
        #pragma unroll
        for (int i = 0; i < 4; ++i)
            op[(g * 4 + i) * O_] = fmaxf(acc[i], 0.f);
    }
}

extern "C" void kernel_launch(void* const* d_in, const int* in_sizes, int n_in,
                              void* d_out, int out_size, void* d_ws, size_t ws_size,
                              hipStream_t stream) {
    const float* x1   = (const float*)d_in[0];
    const float* x2   = (const float*)d_in[1];
    const float* W    = (const float*)d_in[2];
    const float* V    = (const float*)d_in[3];
    const float* bias = (const float*)d_in[4];
    float* out = (float*)d_out;

    __bf16* ubf = (__bf16*)d_ws;                           // 64*2048 bf16 = 256 KB
    float*  c   = (float*)((char*)d_ws + (size_t)B_ * 2048 * sizeof(__bf16));

    prep_kernel<<<dim3(O_, B_), 128, 0, stream>>>(x1, W, V, bias, ubf, c);
    fused_kernel<<<dim3(M_ / 128, B_), 256, 0, stream>>>(x2, ubf, c, out);
}

// Round 7
// 34.455 us; speedup vs baseline: 1.7749x; 1.0106x over previous
//
#include <hip/hip_runtime.h>

#define B_ 64
#define M_ 4096
#define D_ 128
#define O_ 16

typedef __bf16 bf16x8 __attribute__((ext_vector_type(8)));
typedef float  f32x4  __attribute__((ext_vector_type(4)));

// Pass 1: u[b,k,o] = sum_d x1[b,d]*W[o,d,k] + v2[o,k], emitted as bf16 in
// MFMA B-fragment order: lane = kgroup*16 + o, k = kb*32 + kgroup*8 + e.
//         c[b,o] = x1[b].v1[o] + bias[o]
__global__ __launch_bounds__(128) void prep_kernel(
    const float* __restrict__ x1, const float* __restrict__ W,
    const float* __restrict__ V, const float* __restrict__ bias,
    __bf16* __restrict__ ub, float* __restrict__ c)
{
    const int o = blockIdx.x;   // [0,16)
    const int b = blockIdx.y;   // [0,64)
    const int k = threadIdx.x;  // [0,128)
    __shared__ float x1s[D_];
    __shared__ float red[2];
    x1s[k] = x1[b * D_ + k];
    __syncthreads();

    const float* Wo = W + o * D_ * D_;
    float acc = 0.f;
    #pragma unroll 8
    for (int d = 0; d < D_; ++d)
        acc = fmaf(x1s[d], Wo[d * D_ + k], acc);   // coalesced over k

    const float uval = acc + V[o * 2 * D_ + D_ + k];   // + v2[o,k]
    const int e  = k & 7;
    const int g  = (k >> 3) & 3;
    const int kb = k >> 5;
    ub[(size_t)b * 2048 + kb * 512 + g * 128 + o * 8 + e] = (__bf16)uval;

    float p = x1s[k] * V[o * 2 * D_ + k];
    #pragma unroll
    for (int off = 32; off; off >>= 1) p += __shfl_down(p, off, 64);
    if ((k & 63) == 0) red[k >> 6] = p;
    __syncthreads();
    if (k == 0) c[b * O_ + o] = red[0] + red[1] + bias[o];
}

// Pass 2: out[b,m,o] = relu( x2[b,m,:] x u[b,:,:] + c[b,o] ) via MFMA.
// Single-wave blocks (finest scheduling granularity), per-tile register
// staging to keep VGPR <= ~72 so >= 7 waves/SIMD are resident: the whole
// grid is ~one generation and the HBM stream stays saturated end-to-end.
__global__ __launch_bounds__(64, 7) void fused_kernel(
    const float* __restrict__ x2, const __bf16* __restrict__ ub,
    const float* __restrict__ c, float* __restrict__ out)
{
    const int b = blockIdx.y;
    const int lane = threadIdx.x;      // 0..63
    const int rc = lane & 15;          // A-row / C-col (o)
    const int g  = lane >> 4;          // k-group

    // B-fragments straight from global: 1KB/wave-instr coalesced, L2-hot.
    const bf16x8* uf = (const bf16x8*)(ub + (size_t)b * 2048);
    bf16x8 bfrag[4];
    #pragma unroll
    for (int kb = 0; kb < 4; ++kb) bfrag[kb] = uf[kb * 64 + lane];
    const float cv = c[b * O_ + rc];

    const int m_base = blockIdx.x * 32;

    #pragma unroll
    for (int tt = 0; tt < 2; ++tt) {
        const int m0 = m_base + tt * 16;
        // lane reads x2[b][m0+rc][g*8 + kb*32 .. +7]: per instr the wave
        // covers 16 rows x one 128B chunk each, fully coalesced.
        const float4* ap = (const float4*)(x2 + ((size_t)b * M_ + m0 + rc) * D_) + g * 2;
        float4 a[8];
        #pragma unroll
        for (int kb = 0; kb < 4; ++kb) {
            a[kb * 2]     = ap[kb * 8];
            a[kb * 2 + 1] = ap[kb * 8 + 1];
        }

        f32x4 acc = {cv, cv, cv, cv};
        #pragma unroll
        for (int kb = 0; kb < 4; ++kb) {
            const float* p0 = (const float*)&a[kb * 2];
            bf16x8 af;
            af[0] = (__bf16)p0[0]; af[1] = (__bf16)p0[1];
            af[2] = (__bf16)p0[2]; af[3] = (__bf16)p0[3];
            af[4] = (__bf16)p0[4]; af[5] = (__bf16)p0[5];
            af[6] = (__bf16)p0[6]; af[7] = (__bf16)p0[7];
            acc = __builtin_amdgcn_mfma_f32_16x16x32_bf16(af, bfrag[kb], acc, 0, 0, 0);
        }

        // C/D: col = lane&15 (=o), row = g*4 + i  (verified m89/m91)
        float* op = out + ((size_t)b * M_ + m0) * O_ + rc;
        #pragma unroll
        for (int i = 0; i < 4; ++i)
            op[(g * 4 + i) * O_] = fmaxf(acc[i], 0.f);
    }
}

extern "C" void kernel_launch(void* const* d_in, const int* in_sizes, int n_in,
                              void* d_out, int out_size, void* d_ws, size_t ws_size,
                              hipStream_t stream) {
    const float* x1   = (const float*)d_in[0];
    const float* x2   = (const float*)d_in[1];
    const float* W    = (const float*)d_in[2];
    const float* V    = (const float*)d_in[3];
    const float* bias = (const float*)d_in[4];
    float* out = (float*)d_out;

    __bf16* ubf = (__bf16*)d_ws;                           // 64*2048 bf16 = 256 KB
    float*  c   = (float*)((char*)d_ws + (size_t)B_ * 2048 * sizeof(__bf16));

    prep_kernel<<<dim3(O_, B_), 128, 0, stream>>>(x1, W, V, bias, ubf, c);
    fused_kernel<<<dim3(M_ / 32, B_), 64, 0, stream>>>(x2, ubf, c, out);
}